// Round 9
// baseline (3770.537 us; speedup 1.0000x reference)
//
#include <hip/hip_runtime.h>

// SimpleRNN: B=4096, K=512, U=3, P=5, H=128, L=32, N_SUB=10
// R9: 512 blocks x 512 threads (8 waves), 8 batch rows/block -> 2 blocks/CU
// (16 waves/CU). Co-residency hides one block's serial wave-7 chain under
// the other block's work. Lanes col>=8 mirror row col&7 (defined duplicate
// work; column-isolated in all MFMAs). Math identical to R8.
//
// R1: RK4 linear in y -> M = I5 + B*(hs*Z1)*C via T = C*B (4x4 tridiag).
// R2: double-head MFMA: every lane gets all 8 rates directly.
// R3: flux-space iteration (w~ <- G w~, G = I + hs*T*Z1); u/dt LDS ring.
// R5: v_pk_fma_f32 + op_sel broadcast for flux iter / G build / Z1 apply.
// R8: bias C-folding (accumulator resets eliminated).
// NOTE: R6/R7's packed tree/sigm (c) FAILED on HW (asm-VOP3P -> trans
// hazard suspected) — do not reintroduce.

#define KSTEPS 512
#define NTH 512
#define NROWS 8

typedef short s16x8 __attribute__((ext_vector_type(8)));
typedef short s16x4 __attribute__((ext_vector_type(4)));
typedef float f32x4 __attribute__((ext_vector_type(4)));
typedef float f32x2 __attribute__((ext_vector_type(2)));

__device__ __forceinline__ unsigned short f2bf(float f) {
  union { float f; unsigned u; } v; v.f = f;
  unsigned r = v.u + 0x7FFFu + ((v.u >> 16) & 1u);  // RNE
  return (unsigned short)(r >> 16);
}
__device__ __forceinline__ unsigned cvt2bf(float lo, float hi) {
  unsigned r;
  asm("v_cvt_pk_bf16_f32 %0, %1, %2" : "=v"(r) : "v"(lo), "v"(hi));
  return r;
}
__device__ __forceinline__ float ex2(float x) {
#if __has_builtin(__builtin_amdgcn_exp2f)
  return __builtin_amdgcn_exp2f(x);
#else
  return exp2f(x);
#endif
}
__device__ __forceinline__ float rcp_(float x) {
#if __has_builtin(__builtin_amdgcn_rcpf)
  return __builtin_amdgcn_rcpf(x);
#else
  return 1.0f / x;
#endif
}
__device__ __forceinline__ float sigm(float x) {
  return rcp_(1.0f + ex2(-1.44269504088896f * x));
}
__device__ __forceinline__ float tanh_(float x) {
  return fmaf(2.0f, rcp_(1.0f + ex2(-2.88539008177793f * x)), -1.0f);
}
__device__ __forceinline__ f32x4 splat4(float v) { f32x4 r = {v, v, v, v}; return r; }
__device__ __forceinline__ f32x4 MFMA(s16x8 a, s16x8 b, f32x4 c) {
  return __builtin_amdgcn_mfma_f32_16x16x32_bf16(a, b, c, 0, 0, 0);
}
__device__ __forceinline__ s16x8 bfrag_g(const float* __restrict__ src8) {
  s16x8 r;
#pragma unroll
  for (int j = 0; j < 8; ++j) r[j] = (short)f2bf(src8[j]);
  return r;
}

// ---- packed f32 math with op_sel B-broadcast ----
__device__ __forceinline__ f32x2 pkfma_blo(f32x2 a, f32x2 b, f32x2 c) {
  f32x2 d;
  asm("v_pk_fma_f32 %0, %1, %2, %3 op_sel:[0,0,0] op_sel_hi:[1,0,1]"
      : "=v"(d) : "v"(a), "v"(b), "v"(c));
  return d;
}
__device__ __forceinline__ f32x2 pkfma_bhi(f32x2 a, f32x2 b, f32x2 c) {
  f32x2 d;
  asm("v_pk_fma_f32 %0, %1, %2, %3 op_sel:[0,1,0] op_sel_hi:[1,1,1]"
      : "=v"(d) : "v"(a), "v"(b), "v"(c));
  return d;
}
__device__ __forceinline__ f32x2 pkmul_blo(f32x2 a, f32x2 b) {
  f32x2 d;
  asm("v_pk_mul_f32 %0, %1, %2 op_sel:[0,0] op_sel_hi:[1,0]"
      : "=v"(d) : "v"(a), "v"(b));
  return d;
}
__device__ __forceinline__ f32x2 pkmul_bhi(f32x2 a, f32x2 b) {
  f32x2 d;
  asm("v_pk_mul_f32 %0, %1, %2 op_sel:[0,1] op_sel_hi:[1,1]"
      : "=v"(d) : "v"(a), "v"(b));
  return d;
}
__device__ __forceinline__ f32x2 pkadd(f32x2 a, f32x2 b) {
  f32x2 d;
  asm("v_pk_add_f32 %0, %1, %2" : "=v"(d) : "v"(a), "v"(b));
  return d;
}

__global__ __launch_bounds__(NTH, 4) void rnn_scan_kernel(
    const float* __restrict__ y0, const float* __restrict__ u_seq,
    const float* __restrict__ dt_seq, const float* __restrict__ lift_W,
    const float* __restrict__ lift_b, const float* __restrict__ W_ih,
    const float* __restrict__ W_hh, const float* __restrict__ b_ih,
    const float* __restrict__ b_hh, const float* __restrict__ head_W,
    const float* __restrict__ head_b, const float* __restrict__ jumpW,
    float* __restrict__ y_out, float* __restrict__ th_out) {
  __shared__ __align__(16) unsigned short s_Ah[4096];  // h: k=128 -> 4 frags
  __shared__ __align__(16) unsigned short s_Ax[1024];  // x: k=32  -> 1 frag
  __shared__ __align__(16) float s_thr[2][16][8];      // theta ring
  __shared__ __align__(16) float s_yr[2][16][8];       // y ring
  __shared__ __align__(16) float s_ur[3][8][4];        // u/dt ring (8 rows)

  const int tid = threadIdx.x;
  const int w = tid >> 6;      // wave 0..7; wave 7 = critical wave
  const int lane = tid & 63;
  const int quad = lane >> 4;
  const int col = lane & 15;   // batch-row slot in the T-scheme (0..15)
  const int rc = col & 7;      // real row index (cols 8..15 mirror 0..7)
  const int r0 = blockIdx.x << 3;  // 8 rows/block

  s16x8 zf;
#pragma unroll
  for (int j = 0; j < 8; ++j) zf[j] = 0;

  // ---- weight A-frags: A[m=out-col@lane&15][k=quad*8+j] ----
  s16x8 bih_r = bfrag_g(&W_ih[(w * 16 + col) * 32 + quad * 8]);
  s16x8 bih_z = bfrag_g(&W_ih[((8 + w) * 16 + col) * 32 + quad * 8]);
  s16x8 bih_n = bfrag_g(&W_ih[((16 + w) * 16 + col) * 32 + quad * 8]);
  s16x8 bhh_r[4], bhh_z[4], bhh_n[4], bhdF[4], bhdR[4];
#pragma unroll
  for (int s = 0; s < 4; ++s) {
    bhh_r[s] = bfrag_g(&W_hh[(w * 16 + col) * 128 + s * 32 + quad * 8]);
    bhh_z[s] = bfrag_g(&W_hh[((8 + w) * 16 + col) * 128 + s * 32 + quad * 8]);
    bhh_n[s] = bfrag_g(&W_hh[((16 + w) * 16 + col) * 128 + s * 32 + quad * 8]);
    // head rows replicated mod 4: every lane receives kf1..4 / kr1..4.
    bhdF[s] = bfrag_g(&head_W[(col & 3) * 128 + s * 32 + quad * 8]);
    bhdR[s] = bfrag_g(&head_W[(4 + (col & 3)) * 128 + s * 32 + quad * 8]);
  }
  s16x8 blft0 = (quad == 0) ? bfrag_g(&lift_W[col * 8]) : zf;
  s16x8 blft1 = (quad == 0) ? bfrag_g(&lift_W[(16 + col) * 8]) : zf;

  // ---- per-(quad,i) biases ----
  f32x4 brz_r, brz_z, bn_iv, bn_hv, lbv0, lbv1, hbF, hbR;
#pragma unroll
  for (int i = 0; i < 4; ++i) {
    int g = w * 16 + quad * 4 + i;
    brz_r[i] = b_ih[g] + b_hh[g];
    brz_z[i] = b_ih[128 + g] + b_hh[128 + g];
    bn_iv[i] = b_ih[256 + g];
    bn_hv[i] = b_hh[256 + g];
    lbv0[i] = lift_b[quad * 4 + i];
    lbv1[i] = lift_b[16 + quad * 4 + i];
    hbF[i] = head_b[i];
    hbR[i] = head_b[4 + i];
  }
  float J[15];
#pragma unroll
  for (int i = 0; i < 15; ++i) J[i] = jumpW[i];

  // producer LDS byte offsets
  const int hwoff = (((w >> 1) * 64 + ((w & 1) * 2 + (quad >> 1)) * 16 + col) << 4) +
                    ((quad & 1) << 3);
  const int xw0 = ((((quad >> 1)) * 16 + col) << 4) + ((quad & 1) << 3);
  const int xw1 = (((2 + (quad >> 1)) * 16 + col) << 4) + ((quad & 1) << 3);

  // persistent state (ar/az/angh carry bias+gh across barriers; no resets)
  f32x4 ar = brz_r, az = brz_z, angi = bn_iv, angh = bn_hv;
  f32x4 h_reg = splat4(0.0f);
  float y[5] = {0.f, 0.f, 0.f, 0.f, 0.f};

  // ---- prologue ----
  if (w == 1 && lane < NROWS) {
#pragma unroll
    for (int pk = 0; pk < 2; ++pk) {
      const float* up = &u_seq[((size_t)(r0 + lane) * KSTEPS + pk) * 3];
      f32x4 uv;
      uv[0] = up[0]; uv[1] = up[1]; uv[2] = up[2];
      uv[3] = dt_seq[(size_t)(r0 + lane) * KSTEPS + pk];
      *(f32x4*)&s_ur[pk][lane][0] = uv;
    }
  }
  if (w == 7) {
    float uc0 = 0.f, uc1 = 0.f, uc2 = 0.f;
    if (quad == 0) {
      const float* yp = &y0[(r0 + rc) * 5];
#pragma unroll
      for (int i = 0; i < 5; ++i) y[i] = yp[i] + 0.01f;
      const float* up = &u_seq[((size_t)(r0 + rc) * KSTEPS) * 3];
      uc0 = up[0]; uc1 = up[1]; uc2 = up[2];
    }
    s16x8 af = zf;
    if (quad == 0) {
      union { s16x8 v; unsigned u[4]; } afu;
      afu.u[0] = cvt2bf(uc0, uc1);
      afu.u[1] = cvt2bf(uc2, y[0]);
      afu.u[2] = cvt2bf(y[1], y[2]);
      afu.u[3] = cvt2bf(y[3], y[4]);
      af = afu.v;
    }
    f32x4 x0 = MFMA(blft0, af, lbv0);
    f32x4 x1 = MFMA(blft1, af, lbv1);
    f32x4 s0, s1;
#pragma unroll
    for (int i = 0; i < 4; ++i) {
      float v0 = x0[i]; s0[i] = v0 * sigm(v0);
      float v1 = x1[i]; s1[i] = v1 * sigm(v1);
    }
    uint2 xp0, xp1;
    xp0.x = cvt2bf(s0[0], s0[1]); xp0.y = cvt2bf(s0[2], s0[3]);
    xp1.x = cvt2bf(s1[0], s1[1]); xp1.y = cvt2bf(s1[2], s1[3]);
    *(uint2*)((char*)s_Ax + xw0) = xp0;
    *(uint2*)((char*)s_Ax + xw1) = xp1;
  }
  __syncthreads();  // B_x(0)

  int sA = 0, sB = 1, sC = 2;  // u-ring slots

#pragma unroll 1
  for (int k = 0; k < KSTEPS; ++k) {
    // ======== phase 1: gi + gates + h stage (all waves) ========
    {
      s16x8 xf = *(const s16x8*)((const char*)s_Ax + lane * 16);
      ar = MFMA(bih_r, xf, ar);        // carried C = bias + gh(k)
      az = MFMA(bih_z, xf, az);
      angi = MFMA(bih_n, xf, bn_iv);   // bias folded directly
    }
    {
      f32x4 hf;
#pragma unroll
      for (int i = 0; i < 4; ++i) {
        float r = sigm(ar[i]);
        float z = sigm(az[i]);
        float n = tanh_(fmaf(r, angh[i], angi[i]));
        float hn = fmaf(z, h_reg[i] - n, n);
        h_reg[i] = hn;
        hf[i] = hn;
      }
      uint2 hp;
      hp.x = cvt2bf(hf[0], hf[1]);
      hp.y = cvt2bf(hf[2], hf[3]);
      *(uint2*)((char*)s_Ah + hwoff) = hp;
    }
    __syncthreads();  // B_h

    // ======== phase 2 ========
    s16x8 ah[4];
#pragma unroll
    for (int s = 0; s < 4; ++s)
      ah[s] = *(const s16x8*)((const char*)s_Ah + (s * 64 + lane) * 16);

    if (w == 7) {
      __builtin_amdgcn_s_setprio(1);
      f32x4 urk = *(const f32x4*)&s_ur[sA][rc][0];
      f32x4 urk1 = *(const f32x4*)&s_ur[sB][rc][0];
      // head: 8 independent MFMAs
      f32x4 hdF0 = MFMA(bhdF[0], ah[0], hbF);
      f32x4 hdF1 = MFMA(bhdF[1], ah[1], splat4(0.0f));
      f32x4 hdF2 = MFMA(bhdF[2], ah[2], splat4(0.0f));
      f32x4 hdF3 = MFMA(bhdF[3], ah[3], splat4(0.0f));
      f32x4 hdR0 = MFMA(bhdR[0], ah[0], hbR);
      f32x4 hdR1 = MFMA(bhdR[1], ah[1], splat4(0.0f));
      f32x4 hdR2 = MFMA(bhdR[2], ah[2], splat4(0.0f));
      f32x4 hdR3 = MFMA(bhdR[3], ah[3], splat4(0.0f));
      // own gh(k+1) issues under head latency, biases C-folded
      ar = MFMA(bhh_r[0], ah[0], brz_r);
      az = MFMA(bhh_z[0], ah[0], brz_z);
      angh = MFMA(bhh_n[0], ah[0], bn_hv);
#pragma unroll
      for (int s = 1; s < 4; ++s) {
        ar = MFMA(bhh_r[s], ah[s], ar);
        az = MFMA(bhh_z[s], ah[s], az);
        angh = MFMA(bhh_n[s], ah[s], angh);
      }
      f32x4 hdF = (hdF0 + hdF1) + (hdF2 + hdF3);
      f32x4 hdR = (hdR0 + hdR1) + (hdR2 + hdR3);
      f32x4 tvF, tvR;
#pragma unroll
      for (int i = 0; i < 4; ++i) {
        tvF[i] = fmaf(2.99f, sigm(hdF[i]), 0.01f);
        tvR[i] = fmaf(2.99f, sigm(hdR[i]), 0.01f);
      }
      const int slot = k & 1;
      if (quad == 0) {
        *(f32x4*)&s_thr[slot][col][0] = tvF;
        *(f32x4*)&s_thr[slot][col][4] = tvR;
      }
      const float F0 = tvF[0], F1 = tvF[1], F2 = tvF[2], F3 = tvF[3];
      const float R0 = tvR[0], R1 = tvR[1], R2 = tvR[2], R3 = tvR[3];
      // jump
#pragma unroll
      for (int i = 0; i < 5; ++i)
        y[i] += urk[0] * J[i] + urk[1] * J[5 + i] + urk[2] * J[10 + i];
      const float hs = urk[3] * 0.1f;

      // ---- Z1 = I + c2 T(I + c3 T(I + c4 T)) (scalar) ----
      const float TD0 = -(F0 + R0), TD1 = -(F1 + R1), TD2 = -(F2 + R2), TD3 = -(F3 + R3);
      const float c4 = 0.25f * hs, c3 = hs * (1.0f / 3.0f), c2 = 0.5f * hs;
      const float d30 = fmaf(c4, TD0, 1.f), d31 = fmaf(c4, TD1, 1.f);
      const float d32 = fmaf(c4, TD2, 1.f), d33 = fmaf(c4, TD3, 1.f);
      const float l31 = c4 * F1, l32 = c4 * F2, l33 = c4 * F3;
      const float u30 = c4 * R0, u31 = c4 * R1, u32 = c4 * R2;
      const float w300 = fmaf(TD0, d30, R0 * l31);
      const float w301 = fmaf(TD0, u30, R0 * d31);
      const float w302 = R0 * u31;
      const float w310 = fmaf(F1, d30, TD1 * l31);
      const float w311 = fmaf(F1, u30, fmaf(TD1, d31, R1 * l32));
      const float w312 = fmaf(TD1, u31, R1 * d32);
      const float w313 = R1 * u32;
      const float w320 = F2 * l31;
      const float w321 = fmaf(F2, d31, TD2 * l32);
      const float w322 = fmaf(F2, u31, fmaf(TD2, d32, R2 * l33));
      const float w323 = fmaf(TD2, u32, R2 * d33);
      const float w331 = F3 * l32;
      const float w332 = fmaf(F3, d32, TD3 * l33);
      const float w333 = fmaf(F3, u32, TD3 * d33);
      const float e20 = fmaf(c3, w300, 1.f), e21 = fmaf(c3, w311, 1.f);
      const float e22 = fmaf(c3, w322, 1.f), e23 = fmaf(c3, w333, 1.f);
      const float a201 = c3 * w301, a202 = c3 * w302;
      const float a210 = c3 * w310, a212 = c3 * w312, a213 = c3 * w313;
      const float a220 = c3 * w320, a221 = c3 * w321, a223 = c3 * w323;
      const float a231 = c3 * w331, a232 = c3 * w332;
      const float w200 = fmaf(TD0, e20, R0 * a210);
      const float w201 = fmaf(TD0, a201, R0 * e21);
      const float w202 = fmaf(TD0, a202, R0 * a212);
      const float w203 = R0 * a213;
      const float w210 = fmaf(F1, e20, fmaf(TD1, a210, R1 * a220));
      const float w211 = fmaf(F1, a201, fmaf(TD1, e21, R1 * a221));
      const float w212 = fmaf(F1, a202, fmaf(TD1, a212, R1 * e22));
      const float w213 = fmaf(TD1, a213, R1 * a223);
      const float w220 = fmaf(F2, a210, TD2 * a220);
      const float w221 = fmaf(F2, e21, fmaf(TD2, a221, R2 * a231));
      const float w222 = fmaf(F2, a212, fmaf(TD2, e22, R2 * a232));
      const float w223 = fmaf(F2, a213, fmaf(TD2, a223, R2 * e23));
      const float w230 = F3 * a220;
      const float w231 = fmaf(F3, a221, TD3 * a231);
      const float w232 = fmaf(F3, e22, TD3 * a232);
      const float w233 = fmaf(F3, a223, TD3 * e23);
      const float z100 = fmaf(c2, w200, 1.f), z101 = c2 * w201, z102 = c2 * w202, z103 = c2 * w203;
      const float z110 = c2 * w210, z111 = fmaf(c2, w211, 1.f), z112 = c2 * w212, z113 = c2 * w213;
      const float z120 = c2 * w220, z121 = c2 * w221, z122 = fmaf(c2, w222, 1.f), z123 = c2 * w223;
      const float z130 = c2 * w230, z131 = c2 * w231, z132 = c2 * w232, z133 = fmaf(c2, w233, 1.f);

      // ---- packed Z1 columns ----
      f32x2 cZa0 = {z100, z110}, cZb0 = {z120, z130};
      f32x2 cZa1 = {z101, z111}, cZb1 = {z121, z131};
      f32x2 cZa2 = {z102, z112}, cZb2 = {z122, z132};
      f32x2 cZa3 = {z103, z113}, cZb3 = {z123, z133};

      const float FH0 = hs * F0, FH1 = hs * F1, FH2 = hs * F2, FH3 = hs * F3;
      const float RH0 = hs * R0, RH1 = hs * R1, RH2 = hs * R2, RH3 = hs * R3;
      const float TDH0 = -(FH0 + RH0), TDH1 = -(FH1 + RH1);
      const float TDH2 = -(FH2 + RH2), TDH3 = -(FH3 + RH3);
      f32x2 pA01 = {TDH0, FH1}, pB01 = {RH0, TDH1}, pC01 = {0.f, RH1};
      f32x2 pA23 = {FH2, 0.f}, pB23 = {TDH2, FH3}, pC23 = {RH2, TDH3};
      f32x2 cG0a = pkfma_blo(pC01, cZb0, pkfma_bhi(pB01, cZa0, pkmul_blo(pA01, cZa0)));
      f32x2 cG1a = pkfma_blo(pC01, cZb1, pkfma_bhi(pB01, cZa1, pkmul_blo(pA01, cZa1)));
      f32x2 cG2a = pkfma_blo(pC01, cZb2, pkfma_bhi(pB01, cZa2, pkmul_blo(pA01, cZa2)));
      f32x2 cG3a = pkfma_blo(pC01, cZb3, pkfma_bhi(pB01, cZa3, pkmul_blo(pA01, cZa3)));
      f32x2 cG0b = pkfma_bhi(pC23, cZb0, pkfma_blo(pB23, cZb0, pkmul_bhi(pA23, cZa0)));
      f32x2 cG1b = pkfma_bhi(pC23, cZb1, pkfma_blo(pB23, cZb1, pkmul_bhi(pA23, cZa1)));
      f32x2 cG2b = pkfma_bhi(pC23, cZb2, pkfma_blo(pB23, cZb2, pkmul_bhi(pA23, cZa2)));
      f32x2 cG3b = pkfma_bhi(pC23, cZb3, pkfma_blo(pB23, cZb3, pkmul_bhi(pA23, cZa3)));
      cG0a[0] += 1.0f;
      cG1a[1] += 1.0f;
      cG2b[0] += 1.0f;
      cG3b[1] += 1.0f;

      // w~0 = hs*C*y
      const float w0v = fmaf(FH0, y[0], -(RH0 * y[1]));
      const float w1v = fmaf(FH1, y[1], -(RH1 * y[2]));
      const float w2v = fmaf(FH2, y[2], -(RH2 * y[3]));
      const float w3v = fmaf(FH3, y[3], -(RH3 * y[4]));
      f32x2 W01 = {w0v, w1v}, W23 = {w2v, w3v};
      f32x2 A01 = W01, A23 = W23;
#pragma unroll
      for (int ss = 0; ss < 9; ++ss) {
        f32x2 m01 = pkfma_blo(cG0a, W01,
                    pkfma_bhi(cG1a, W01,
                    pkfma_blo(cG2a, W23, pkmul_bhi(cG3a, W23))));
        f32x2 m23 = pkfma_blo(cG0b, W01,
                    pkfma_bhi(cG1b, W01,
                    pkfma_blo(cG2b, W23, pkmul_bhi(cG3b, W23))));
        W01 = m01; W23 = m23;
        A01 = pkadd(A01, m01); A23 = pkadd(A23, m23);
      }
      f32x2 s01 = pkfma_blo(cZa0, A01,
                  pkfma_bhi(cZa1, A01,
                  pkfma_blo(cZa2, A23, pkmul_bhi(cZa3, A23))));
      f32x2 s23 = pkfma_blo(cZb0, A01,
                  pkfma_bhi(cZb1, A01,
                  pkfma_blo(cZb2, A23, pkmul_bhi(cZb3, A23))));
      const float s0f = s01[0], s1f = s01[1], s2f = s23[0], s3f = s23[1];
      y[0] -= s0f;
      y[1] += s0f - s1f;
      y[2] += s1f - s2f;
      y[3] += s2f - s3f;
      y[4] += s3f;
      if (quad == 0) {
        *(f32x4*)&s_yr[slot][col][0] = *(const f32x4*)&y[0];
        s_yr[slot][col][4] = y[4];
      }
      // feat(k+1) -> liftT -> silu -> x stage
      if (k + 1 < KSTEPS) {
        s16x8 af = zf;
        if (quad == 0) {
          union { s16x8 v; unsigned u[4]; } afu;
          afu.u[0] = cvt2bf(urk1[0], urk1[1]);
          afu.u[1] = cvt2bf(urk1[2], y[0]);
          afu.u[2] = cvt2bf(y[1], y[2]);
          afu.u[3] = cvt2bf(y[3], y[4]);
          af = afu.v;
        }
        f32x4 x0 = MFMA(blft0, af, lbv0);
        f32x4 x1 = MFMA(blft1, af, lbv1);
        f32x4 s0, s1;
#pragma unroll
        for (int i = 0; i < 4; ++i) {
          float v0 = x0[i]; s0[i] = v0 * sigm(v0);
          float v1 = x1[i]; s1[i] = v1 * sigm(v1);
        }
        uint2 xp0, xp1;
        xp0.x = cvt2bf(s0[0], s0[1]); xp0.y = cvt2bf(s0[2], s0[3]);
        xp1.x = cvt2bf(s1[0], s1[1]); xp1.y = cvt2bf(s1[2], s1[3]);
        *(uint2*)((char*)s_Ax + xw0) = xp0;
        *(uint2*)((char*)s_Ax + xw1) = xp1;
      }
      __builtin_amdgcn_s_setprio(0);
    } else {
      // gh(k+1) for this wave's tile, biases C-folded
      ar = MFMA(bhh_r[0], ah[0], brz_r);
      az = MFMA(bhh_z[0], ah[0], brz_z);
      angh = MFMA(bhh_n[0], ah[0], bn_hv);
#pragma unroll
      for (int s = 1; s < 4; ++s) {
        ar = MFMA(bhh_r[s], ah[s], ar);
        az = MFMA(bhh_z[s], ah[s], az);
        angh = MFMA(bhh_n[s], ah[s], angh);
      }
      if (w == 1 && lane < NROWS) {  // stage u/dt for step k+2
        int kn2 = (k + 2 < KSTEPS) ? k + 2 : KSTEPS - 1;
        const float* up = &u_seq[((size_t)(r0 + lane) * KSTEPS + kn2) * 3];
        f32x4 uv;
        uv[0] = up[0]; uv[1] = up[1]; uv[2] = up[2];
        uv[3] = dt_seq[(size_t)(r0 + lane) * KSTEPS + kn2];
        *(f32x4*)&s_ur[sC][lane][0] = uv;
      }
      if (w == 0 && k > 0) {  // store step k-1 outputs (8 rows)
        const int km = k - 1, slot = km & 1;
        {
          int row = lane >> 3, c = lane & 7;  // 64 theta values
          th_out[((size_t)(r0 + row) * KSTEPS + km) * 8 + c] = s_thr[slot][row][c];
        }
        if (lane < 40) {  // 40 y values
          int row = lane / 5, c = lane - row * 5;
          y_out[((size_t)(r0 + row) * KSTEPS + km) * 5 + c] = s_yr[slot][row][c];
        }
      }
    }
    __syncthreads();  // B_x: x(k+1) staged, s_Ah + s_ur[sC] reusable
    int st = sA; sA = sB; sB = sC; sC = st;
  }

  // flush step-511 outputs (8 rows)
  if (w == 0) {
    const int km = KSTEPS - 1, slot = km & 1;
    {
      int row = lane >> 3, c = lane & 7;
      th_out[((size_t)(r0 + row) * KSTEPS + km) * 8 + c] = s_thr[slot][row][c];
    }
    if (lane < 40) {
      int row = lane / 5, c = lane - row * 5;
      y_out[((size_t)(r0 + row) * KSTEPS + km) * 5 + c] = s_yr[slot][row][c];
    }
  }
}

extern "C" void kernel_launch(void* const* d_in, const int* in_sizes, int n_in,
                              void* d_out, int out_size, void* d_ws, size_t ws_size,
                              hipStream_t stream) {
  const float* y0 = (const float*)d_in[0];
  const float* u_seq = (const float*)d_in[1];
  const float* dt_seq = (const float*)d_in[2];
  const float* lift_W = (const float*)d_in[3];
  const float* lift_b = (const float*)d_in[4];
  const float* W_ih = (const float*)d_in[5];
  const float* W_hh = (const float*)d_in[6];
  const float* b_ih = (const float*)d_in[7];
  const float* b_hh = (const float*)d_in[8];
  const float* head_W = (const float*)d_in[9];
  const float* head_b = (const float*)d_in[10];
  const float* jumpW = (const float*)d_in[11];

  float* y_out = (float*)d_out;                    // (4096, 512, 5)
  float* th_out = y_out + (size_t)4096 * 512 * 5;  // (4096, 512, 8)

  rnn_scan_kernel<<<dim3(512), dim3(NTH), 0, stream>>>(
      y0, u_seq, dt_seq, lift_W, lift_b, W_ih, W_hh, b_ih, b_hh, head_W,
      head_b, jumpW, y_out, th_out);
}

// Round 10
// 1762.316 us; speedup vs baseline: 2.1395x; 2.1395x over previous
//
#include <hip/hip_runtime.h>

// SimpleRNN: B=4096, K=512, U=3, P=5, H=128, L=32, N_SUB=10
// R10: 512 blocks x 512 threads (8 waves), 8 batch rows/block -> 2 blocks/CU
// (16 waves/CU). Co-residency hides one block's serial wave-7 chain under
// the other block's work. Lanes col>=8 mirror row col&7 (defined duplicate
// work; column-isolated in all MFMAs). Math identical to R8.
// LAUNCH BOUNDS LESSON (R9 counters): hipcc treats the 2nd arg as
// blocks/CU here — (512,4) capped VGPR at 64 (8 waves/EU) and spilled the
// loop-invariant weight frags to scratch (FETCH 4.7 GB/dispatch, 4x slower).
// (512,2) -> 128-VGPR cap, which this body compiles to exactly (R8), and
// still admits 16 waves/CU = 2 blocks/CU.
//
// R1: RK4 linear in y -> M = I5 + B*(hs*Z1)*C via T = C*B (4x4 tridiag).
// R2: double-head MFMA: every lane gets all 8 rates directly.
// R3: flux-space iteration (w~ <- G w~, G = I + hs*T*Z1); u/dt LDS ring.
// R5: v_pk_fma_f32 + op_sel broadcast for flux iter / G build / Z1 apply.
// R8: bias C-folding (accumulator resets eliminated).
// NOTE: R6/R7's packed tree/sigm FAILED on HW (asm-VOP3P -> trans hazard
// suspected) — do not reintroduce.

#define KSTEPS 512
#define NTH 512
#define NROWS 8

typedef short s16x8 __attribute__((ext_vector_type(8)));
typedef short s16x4 __attribute__((ext_vector_type(4)));
typedef float f32x4 __attribute__((ext_vector_type(4)));
typedef float f32x2 __attribute__((ext_vector_type(2)));

__device__ __forceinline__ unsigned short f2bf(float f) {
  union { float f; unsigned u; } v; v.f = f;
  unsigned r = v.u + 0x7FFFu + ((v.u >> 16) & 1u);  // RNE
  return (unsigned short)(r >> 16);
}
__device__ __forceinline__ unsigned cvt2bf(float lo, float hi) {
  unsigned r;
  asm("v_cvt_pk_bf16_f32 %0, %1, %2" : "=v"(r) : "v"(lo), "v"(hi));
  return r;
}
__device__ __forceinline__ float ex2(float x) {
#if __has_builtin(__builtin_amdgcn_exp2f)
  return __builtin_amdgcn_exp2f(x);
#else
  return exp2f(x);
#endif
}
__device__ __forceinline__ float rcp_(float x) {
#if __has_builtin(__builtin_amdgcn_rcpf)
  return __builtin_amdgcn_rcpf(x);
#else
  return 1.0f / x;
#endif
}
__device__ __forceinline__ float sigm(float x) {
  return rcp_(1.0f + ex2(-1.44269504088896f * x));
}
__device__ __forceinline__ float tanh_(float x) {
  return fmaf(2.0f, rcp_(1.0f + ex2(-2.88539008177793f * x)), -1.0f);
}
__device__ __forceinline__ f32x4 splat4(float v) { f32x4 r = {v, v, v, v}; return r; }
__device__ __forceinline__ f32x4 MFMA(s16x8 a, s16x8 b, f32x4 c) {
  return __builtin_amdgcn_mfma_f32_16x16x32_bf16(a, b, c, 0, 0, 0);
}
__device__ __forceinline__ s16x8 bfrag_g(const float* __restrict__ src8) {
  s16x8 r;
#pragma unroll
  for (int j = 0; j < 8; ++j) r[j] = (short)f2bf(src8[j]);
  return r;
}

// ---- packed f32 math with op_sel B-broadcast ----
__device__ __forceinline__ f32x2 pkfma_blo(f32x2 a, f32x2 b, f32x2 c) {
  f32x2 d;
  asm("v_pk_fma_f32 %0, %1, %2, %3 op_sel:[0,0,0] op_sel_hi:[1,0,1]"
      : "=v"(d) : "v"(a), "v"(b), "v"(c));
  return d;
}
__device__ __forceinline__ f32x2 pkfma_bhi(f32x2 a, f32x2 b, f32x2 c) {
  f32x2 d;
  asm("v_pk_fma_f32 %0, %1, %2, %3 op_sel:[0,1,0] op_sel_hi:[1,1,1]"
      : "=v"(d) : "v"(a), "v"(b), "v"(c));
  return d;
}
__device__ __forceinline__ f32x2 pkmul_blo(f32x2 a, f32x2 b) {
  f32x2 d;
  asm("v_pk_mul_f32 %0, %1, %2 op_sel:[0,0] op_sel_hi:[1,0]"
      : "=v"(d) : "v"(a), "v"(b));
  return d;
}
__device__ __forceinline__ f32x2 pkmul_bhi(f32x2 a, f32x2 b) {
  f32x2 d;
  asm("v_pk_mul_f32 %0, %1, %2 op_sel:[0,1] op_sel_hi:[1,1]"
      : "=v"(d) : "v"(a), "v"(b));
  return d;
}
__device__ __forceinline__ f32x2 pkadd(f32x2 a, f32x2 b) {
  f32x2 d;
  asm("v_pk_add_f32 %0, %1, %2" : "=v"(d) : "v"(a), "v"(b));
  return d;
}

__global__ __launch_bounds__(NTH, 2) void rnn_scan_kernel(
    const float* __restrict__ y0, const float* __restrict__ u_seq,
    const float* __restrict__ dt_seq, const float* __restrict__ lift_W,
    const float* __restrict__ lift_b, const float* __restrict__ W_ih,
    const float* __restrict__ W_hh, const float* __restrict__ b_ih,
    const float* __restrict__ b_hh, const float* __restrict__ head_W,
    const float* __restrict__ head_b, const float* __restrict__ jumpW,
    float* __restrict__ y_out, float* __restrict__ th_out) {
  __shared__ __align__(16) unsigned short s_Ah[4096];  // h: k=128 -> 4 frags
  __shared__ __align__(16) unsigned short s_Ax[1024];  // x: k=32  -> 1 frag
  __shared__ __align__(16) float s_thr[2][16][8];      // theta ring
  __shared__ __align__(16) float s_yr[2][16][8];       // y ring
  __shared__ __align__(16) float s_ur[3][8][4];        // u/dt ring (8 rows)

  const int tid = threadIdx.x;
  const int w = tid >> 6;      // wave 0..7; wave 7 = critical wave
  const int lane = tid & 63;
  const int quad = lane >> 4;
  const int col = lane & 15;   // batch-row slot in the T-scheme (0..15)
  const int rc = col & 7;      // real row index (cols 8..15 mirror 0..7)
  const int r0 = blockIdx.x << 3;  // 8 rows/block

  s16x8 zf;
#pragma unroll
  for (int j = 0; j < 8; ++j) zf[j] = 0;

  // ---- weight A-frags: A[m=out-col@lane&15][k=quad*8+j] ----
  s16x8 bih_r = bfrag_g(&W_ih[(w * 16 + col) * 32 + quad * 8]);
  s16x8 bih_z = bfrag_g(&W_ih[((8 + w) * 16 + col) * 32 + quad * 8]);
  s16x8 bih_n = bfrag_g(&W_ih[((16 + w) * 16 + col) * 32 + quad * 8]);
  s16x8 bhh_r[4], bhh_z[4], bhh_n[4], bhdF[4], bhdR[4];
#pragma unroll
  for (int s = 0; s < 4; ++s) {
    bhh_r[s] = bfrag_g(&W_hh[(w * 16 + col) * 128 + s * 32 + quad * 8]);
    bhh_z[s] = bfrag_g(&W_hh[((8 + w) * 16 + col) * 128 + s * 32 + quad * 8]);
    bhh_n[s] = bfrag_g(&W_hh[((16 + w) * 16 + col) * 128 + s * 32 + quad * 8]);
    // head rows replicated mod 4: every lane receives kf1..4 / kr1..4.
    bhdF[s] = bfrag_g(&head_W[(col & 3) * 128 + s * 32 + quad * 8]);
    bhdR[s] = bfrag_g(&head_W[(4 + (col & 3)) * 128 + s * 32 + quad * 8]);
  }
  s16x8 blft0 = (quad == 0) ? bfrag_g(&lift_W[col * 8]) : zf;
  s16x8 blft1 = (quad == 0) ? bfrag_g(&lift_W[(16 + col) * 8]) : zf;

  // ---- per-(quad,i) biases ----
  f32x4 brz_r, brz_z, bn_iv, bn_hv, lbv0, lbv1, hbF, hbR;
#pragma unroll
  for (int i = 0; i < 4; ++i) {
    int g = w * 16 + quad * 4 + i;
    brz_r[i] = b_ih[g] + b_hh[g];
    brz_z[i] = b_ih[128 + g] + b_hh[128 + g];
    bn_iv[i] = b_ih[256 + g];
    bn_hv[i] = b_hh[256 + g];
    lbv0[i] = lift_b[quad * 4 + i];
    lbv1[i] = lift_b[16 + quad * 4 + i];
    hbF[i] = head_b[i];
    hbR[i] = head_b[4 + i];
  }
  float J[15];
#pragma unroll
  for (int i = 0; i < 15; ++i) J[i] = jumpW[i];

  // producer LDS byte offsets
  const int hwoff = (((w >> 1) * 64 + ((w & 1) * 2 + (quad >> 1)) * 16 + col) << 4) +
                    ((quad & 1) << 3);
  const int xw0 = ((((quad >> 1)) * 16 + col) << 4) + ((quad & 1) << 3);
  const int xw1 = (((2 + (quad >> 1)) * 16 + col) << 4) + ((quad & 1) << 3);

  // persistent state (ar/az/angh carry bias+gh across barriers; no resets)
  f32x4 ar = brz_r, az = brz_z, angi = bn_iv, angh = bn_hv;
  f32x4 h_reg = splat4(0.0f);
  float y[5] = {0.f, 0.f, 0.f, 0.f, 0.f};

  // ---- prologue ----
  if (w == 1 && lane < NROWS) {
#pragma unroll
    for (int pk = 0; pk < 2; ++pk) {
      const float* up = &u_seq[((size_t)(r0 + lane) * KSTEPS + pk) * 3];
      f32x4 uv;
      uv[0] = up[0]; uv[1] = up[1]; uv[2] = up[2];
      uv[3] = dt_seq[(size_t)(r0 + lane) * KSTEPS + pk];
      *(f32x4*)&s_ur[pk][lane][0] = uv;
    }
  }
  if (w == 7) {
    float uc0 = 0.f, uc1 = 0.f, uc2 = 0.f;
    if (quad == 0) {
      const float* yp = &y0[(r0 + rc) * 5];
#pragma unroll
      for (int i = 0; i < 5; ++i) y[i] = yp[i] + 0.01f;
      const float* up = &u_seq[((size_t)(r0 + rc) * KSTEPS) * 3];
      uc0 = up[0]; uc1 = up[1]; uc2 = up[2];
    }
    s16x8 af = zf;
    if (quad == 0) {
      union { s16x8 v; unsigned u[4]; } afu;
      afu.u[0] = cvt2bf(uc0, uc1);
      afu.u[1] = cvt2bf(uc2, y[0]);
      afu.u[2] = cvt2bf(y[1], y[2]);
      afu.u[3] = cvt2bf(y[3], y[4]);
      af = afu.v;
    }
    f32x4 x0 = MFMA(blft0, af, lbv0);
    f32x4 x1 = MFMA(blft1, af, lbv1);
    f32x4 s0, s1;
#pragma unroll
    for (int i = 0; i < 4; ++i) {
      float v0 = x0[i]; s0[i] = v0 * sigm(v0);
      float v1 = x1[i]; s1[i] = v1 * sigm(v1);
    }
    uint2 xp0, xp1;
    xp0.x = cvt2bf(s0[0], s0[1]); xp0.y = cvt2bf(s0[2], s0[3]);
    xp1.x = cvt2bf(s1[0], s1[1]); xp1.y = cvt2bf(s1[2], s1[3]);
    *(uint2*)((char*)s_Ax + xw0) = xp0;
    *(uint2*)((char*)s_Ax + xw1) = xp1;
  }
  __syncthreads();  // B_x(0)

  int sA = 0, sB = 1, sC = 2;  // u-ring slots

#pragma unroll 1
  for (int k = 0; k < KSTEPS; ++k) {
    // ======== phase 1: gi + gates + h stage (all waves) ========
    {
      s16x8 xf = *(const s16x8*)((const char*)s_Ax + lane * 16);
      ar = MFMA(bih_r, xf, ar);        // carried C = bias + gh(k)
      az = MFMA(bih_z, xf, az);
      angi = MFMA(bih_n, xf, bn_iv);   // bias folded directly
    }
    {
      f32x4 hf;
#pragma unroll
      for (int i = 0; i < 4; ++i) {
        float r = sigm(ar[i]);
        float z = sigm(az[i]);
        float n = tanh_(fmaf(r, angh[i], angi[i]));
        float hn = fmaf(z, h_reg[i] - n, n);
        h_reg[i] = hn;
        hf[i] = hn;
      }
      uint2 hp;
      hp.x = cvt2bf(hf[0], hf[1]);
      hp.y = cvt2bf(hf[2], hf[3]);
      *(uint2*)((char*)s_Ah + hwoff) = hp;
    }
    __syncthreads();  // B_h

    // ======== phase 2 ========
    s16x8 ah[4];
#pragma unroll
    for (int s = 0; s < 4; ++s)
      ah[s] = *(const s16x8*)((const char*)s_Ah + (s * 64 + lane) * 16);

    if (w == 7) {
      __builtin_amdgcn_s_setprio(1);
      f32x4 urk = *(const f32x4*)&s_ur[sA][rc][0];
      f32x4 urk1 = *(const f32x4*)&s_ur[sB][rc][0];
      // head: 8 independent MFMAs
      f32x4 hdF0 = MFMA(bhdF[0], ah[0], hbF);
      f32x4 hdF1 = MFMA(bhdF[1], ah[1], splat4(0.0f));
      f32x4 hdF2 = MFMA(bhdF[2], ah[2], splat4(0.0f));
      f32x4 hdF3 = MFMA(bhdF[3], ah[3], splat4(0.0f));
      f32x4 hdR0 = MFMA(bhdR[0], ah[0], hbR);
      f32x4 hdR1 = MFMA(bhdR[1], ah[1], splat4(0.0f));
      f32x4 hdR2 = MFMA(bhdR[2], ah[2], splat4(0.0f));
      f32x4 hdR3 = MFMA(bhdR[3], ah[3], splat4(0.0f));
      // own gh(k+1) issues under head latency, biases C-folded
      ar = MFMA(bhh_r[0], ah[0], brz_r);
      az = MFMA(bhh_z[0], ah[0], brz_z);
      angh = MFMA(bhh_n[0], ah[0], bn_hv);
#pragma unroll
      for (int s = 1; s < 4; ++s) {
        ar = MFMA(bhh_r[s], ah[s], ar);
        az = MFMA(bhh_z[s], ah[s], az);
        angh = MFMA(bhh_n[s], ah[s], angh);
      }
      f32x4 hdF = (hdF0 + hdF1) + (hdF2 + hdF3);
      f32x4 hdR = (hdR0 + hdR1) + (hdR2 + hdR3);
      f32x4 tvF, tvR;
#pragma unroll
      for (int i = 0; i < 4; ++i) {
        tvF[i] = fmaf(2.99f, sigm(hdF[i]), 0.01f);
        tvR[i] = fmaf(2.99f, sigm(hdR[i]), 0.01f);
      }
      const int slot = k & 1;
      if (quad == 0) {
        *(f32x4*)&s_thr[slot][col][0] = tvF;
        *(f32x4*)&s_thr[slot][col][4] = tvR;
      }
      const float F0 = tvF[0], F1 = tvF[1], F2 = tvF[2], F3 = tvF[3];
      const float R0 = tvR[0], R1 = tvR[1], R2 = tvR[2], R3 = tvR[3];
      // jump
#pragma unroll
      for (int i = 0; i < 5; ++i)
        y[i] += urk[0] * J[i] + urk[1] * J[5 + i] + urk[2] * J[10 + i];
      const float hs = urk[3] * 0.1f;

      // ---- Z1 = I + c2 T(I + c3 T(I + c4 T)) (scalar) ----
      const float TD0 = -(F0 + R0), TD1 = -(F1 + R1), TD2 = -(F2 + R2), TD3 = -(F3 + R3);
      const float c4 = 0.25f * hs, c3 = hs * (1.0f / 3.0f), c2 = 0.5f * hs;
      const float d30 = fmaf(c4, TD0, 1.f), d31 = fmaf(c4, TD1, 1.f);
      const float d32 = fmaf(c4, TD2, 1.f), d33 = fmaf(c4, TD3, 1.f);
      const float l31 = c4 * F1, l32 = c4 * F2, l33 = c4 * F3;
      const float u30 = c4 * R0, u31 = c4 * R1, u32 = c4 * R2;
      const float w300 = fmaf(TD0, d30, R0 * l31);
      const float w301 = fmaf(TD0, u30, R0 * d31);
      const float w302 = R0 * u31;
      const float w310 = fmaf(F1, d30, TD1 * l31);
      const float w311 = fmaf(F1, u30, fmaf(TD1, d31, R1 * l32));
      const float w312 = fmaf(TD1, u31, R1 * d32);
      const float w313 = R1 * u32;
      const float w320 = F2 * l31;
      const float w321 = fmaf(F2, d31, TD2 * l32);
      const float w322 = fmaf(F2, u31, fmaf(TD2, d32, R2 * l33));
      const float w323 = fmaf(TD2, u32, R2 * d33);
      const float w331 = F3 * l32;
      const float w332 = fmaf(F3, d32, TD3 * l33);
      const float w333 = fmaf(F3, u32, TD3 * d33);
      const float e20 = fmaf(c3, w300, 1.f), e21 = fmaf(c3, w311, 1.f);
      const float e22 = fmaf(c3, w322, 1.f), e23 = fmaf(c3, w333, 1.f);
      const float a201 = c3 * w301, a202 = c3 * w302;
      const float a210 = c3 * w310, a212 = c3 * w312, a213 = c3 * w313;
      const float a220 = c3 * w320, a221 = c3 * w321, a223 = c3 * w323;
      const float a231 = c3 * w331, a232 = c3 * w332;
      const float w200 = fmaf(TD0, e20, R0 * a210);
      const float w201 = fmaf(TD0, a201, R0 * e21);
      const float w202 = fmaf(TD0, a202, R0 * a212);
      const float w203 = R0 * a213;
      const float w210 = fmaf(F1, e20, fmaf(TD1, a210, R1 * a220));
      const float w211 = fmaf(F1, a201, fmaf(TD1, e21, R1 * a221));
      const float w212 = fmaf(F1, a202, fmaf(TD1, a212, R1 * e22));
      const float w213 = fmaf(TD1, a213, R1 * a223);
      const float w220 = fmaf(F2, a210, TD2 * a220);
      const float w221 = fmaf(F2, e21, fmaf(TD2, a221, R2 * a231));
      const float w222 = fmaf(F2, a212, fmaf(TD2, e22, R2 * a232));
      const float w223 = fmaf(F2, a213, fmaf(TD2, a223, R2 * e23));
      const float w230 = F3 * a220;
      const float w231 = fmaf(F3, a221, TD3 * a231);
      const float w232 = fmaf(F3, e22, TD3 * a232);
      const float w233 = fmaf(F3, a223, TD3 * e23);
      const float z100 = fmaf(c2, w200, 1.f), z101 = c2 * w201, z102 = c2 * w202, z103 = c2 * w203;
      const float z110 = c2 * w210, z111 = fmaf(c2, w211, 1.f), z112 = c2 * w212, z113 = c2 * w213;
      const float z120 = c2 * w220, z121 = c2 * w221, z122 = fmaf(c2, w222, 1.f), z123 = c2 * w223;
      const float z130 = c2 * w230, z131 = c2 * w231, z132 = c2 * w232, z133 = fmaf(c2, w233, 1.f);

      // ---- packed Z1 columns ----
      f32x2 cZa0 = {z100, z110}, cZb0 = {z120, z130};
      f32x2 cZa1 = {z101, z111}, cZb1 = {z121, z131};
      f32x2 cZa2 = {z102, z112}, cZb2 = {z122, z132};
      f32x2 cZa3 = {z103, z113}, cZb3 = {z123, z133};

      const float FH0 = hs * F0, FH1 = hs * F1, FH2 = hs * F2, FH3 = hs * F3;
      const float RH0 = hs * R0, RH1 = hs * R1, RH2 = hs * R2, RH3 = hs * R3;
      const float TDH0 = -(FH0 + RH0), TDH1 = -(FH1 + RH1);
      const float TDH2 = -(FH2 + RH2), TDH3 = -(FH3 + RH3);
      f32x2 pA01 = {TDH0, FH1}, pB01 = {RH0, TDH1}, pC01 = {0.f, RH1};
      f32x2 pA23 = {FH2, 0.f}, pB23 = {TDH2, FH3}, pC23 = {RH2, TDH3};
      f32x2 cG0a = pkfma_blo(pC01, cZb0, pkfma_bhi(pB01, cZa0, pkmul_blo(pA01, cZa0)));
      f32x2 cG1a = pkfma_blo(pC01, cZb1, pkfma_bhi(pB01, cZa1, pkmul_blo(pA01, cZa1)));
      f32x2 cG2a = pkfma_blo(pC01, cZb2, pkfma_bhi(pB01, cZa2, pkmul_blo(pA01, cZa2)));
      f32x2 cG3a = pkfma_blo(pC01, cZb3, pkfma_bhi(pB01, cZa3, pkmul_blo(pA01, cZa3)));
      f32x2 cG0b = pkfma_bhi(pC23, cZb0, pkfma_blo(pB23, cZb0, pkmul_bhi(pA23, cZa0)));
      f32x2 cG1b = pkfma_bhi(pC23, cZb1, pkfma_blo(pB23, cZb1, pkmul_bhi(pA23, cZa1)));
      f32x2 cG2b = pkfma_bhi(pC23, cZb2, pkfma_blo(pB23, cZb2, pkmul_bhi(pA23, cZa2)));
      f32x2 cG3b = pkfma_bhi(pC23, cZb3, pkfma_blo(pB23, cZb3, pkmul_bhi(pA23, cZa3)));
      cG0a[0] += 1.0f;
      cG1a[1] += 1.0f;
      cG2b[0] += 1.0f;
      cG3b[1] += 1.0f;

      // w~0 = hs*C*y
      const float w0v = fmaf(FH0, y[0], -(RH0 * y[1]));
      const float w1v = fmaf(FH1, y[1], -(RH1 * y[2]));
      const float w2v = fmaf(FH2, y[2], -(RH2 * y[3]));
      const float w3v = fmaf(FH3, y[3], -(RH3 * y[4]));
      f32x2 W01 = {w0v, w1v}, W23 = {w2v, w3v};
      f32x2 A01 = W01, A23 = W23;
#pragma unroll
      for (int ss = 0; ss < 9; ++ss) {
        f32x2 m01 = pkfma_blo(cG0a, W01,
                    pkfma_bhi(cG1a, W01,
                    pkfma_blo(cG2a, W23, pkmul_bhi(cG3a, W23))));
        f32x2 m23 = pkfma_blo(cG0b, W01,
                    pkfma_bhi(cG1b, W01,
                    pkfma_blo(cG2b, W23, pkmul_bhi(cG3b, W23))));
        W01 = m01; W23 = m23;
        A01 = pkadd(A01, m01); A23 = pkadd(A23, m23);
      }
      f32x2 s01 = pkfma_blo(cZa0, A01,
                  pkfma_bhi(cZa1, A01,
                  pkfma_blo(cZa2, A23, pkmul_bhi(cZa3, A23))));
      f32x2 s23 = pkfma_blo(cZb0, A01,
                  pkfma_bhi(cZb1, A01,
                  pkfma_blo(cZb2, A23, pkmul_bhi(cZb3, A23))));
      const float s0f = s01[0], s1f = s01[1], s2f = s23[0], s3f = s23[1];
      y[0] -= s0f;
      y[1] += s0f - s1f;
      y[2] += s1f - s2f;
      y[3] += s2f - s3f;
      y[4] += s3f;
      if (quad == 0) {
        *(f32x4*)&s_yr[slot][col][0] = *(const f32x4*)&y[0];
        s_yr[slot][col][4] = y[4];
      }
      // feat(k+1) -> liftT -> silu -> x stage
      if (k + 1 < KSTEPS) {
        s16x8 af = zf;
        if (quad == 0) {
          union { s16x8 v; unsigned u[4]; } afu;
          afu.u[0] = cvt2bf(urk1[0], urk1[1]);
          afu.u[1] = cvt2bf(urk1[2], y[0]);
          afu.u[2] = cvt2bf(y[1], y[2]);
          afu.u[3] = cvt2bf(y[3], y[4]);
          af = afu.v;
        }
        f32x4 x0 = MFMA(blft0, af, lbv0);
        f32x4 x1 = MFMA(blft1, af, lbv1);
        f32x4 s0, s1;
#pragma unroll
        for (int i = 0; i < 4; ++i) {
          float v0 = x0[i]; s0[i] = v0 * sigm(v0);
          float v1 = x1[i]; s1[i] = v1 * sigm(v1);
        }
        uint2 xp0, xp1;
        xp0.x = cvt2bf(s0[0], s0[1]); xp0.y = cvt2bf(s0[2], s0[3]);
        xp1.x = cvt2bf(s1[0], s1[1]); xp1.y = cvt2bf(s1[2], s1[3]);
        *(uint2*)((char*)s_Ax + xw0) = xp0;
        *(uint2*)((char*)s_Ax + xw1) = xp1;
      }
      __builtin_amdgcn_s_setprio(0);
    } else {
      // gh(k+1) for this wave's tile, biases C-folded
      ar = MFMA(bhh_r[0], ah[0], brz_r);
      az = MFMA(bhh_z[0], ah[0], brz_z);
      angh = MFMA(bhh_n[0], ah[0], bn_hv);
#pragma unroll
      for (int s = 1; s < 4; ++s) {
        ar = MFMA(bhh_r[s], ah[s], ar);
        az = MFMA(bhh_z[s], ah[s], az);
        angh = MFMA(bhh_n[s], ah[s], angh);
      }
      if (w == 1 && lane < NROWS) {  // stage u/dt for step k+2
        int kn2 = (k + 2 < KSTEPS) ? k + 2 : KSTEPS - 1;
        const float* up = &u_seq[((size_t)(r0 + lane) * KSTEPS + kn2) * 3];
        f32x4 uv;
        uv[0] = up[0]; uv[1] = up[1]; uv[2] = up[2];
        uv[3] = dt_seq[(size_t)(r0 + lane) * KSTEPS + kn2];
        *(f32x4*)&s_ur[sC][lane][0] = uv;
      }
      if (w == 0 && k > 0) {  // store step k-1 outputs (8 rows)
        const int km = k - 1, slot = km & 1;
        {
          int row = lane >> 3, c = lane & 7;  // 64 theta values
          th_out[((size_t)(r0 + row) * KSTEPS + km) * 8 + c] = s_thr[slot][row][c];
        }
        if (lane < 40) {  // 40 y values
          int row = lane / 5, c = lane - row * 5;
          y_out[((size_t)(r0 + row) * KSTEPS + km) * 5 + c] = s_yr[slot][row][c];
        }
      }
    }
    __syncthreads();  // B_x: x(k+1) staged, s_Ah + s_ur[sC] reusable
    int st = sA; sA = sB; sB = sC; sC = st;
  }

  // flush step-511 outputs (8 rows)
  if (w == 0) {
    const int km = KSTEPS - 1, slot = km & 1;
    {
      int row = lane >> 3, c = lane & 7;
      th_out[((size_t)(r0 + row) * KSTEPS + km) * 8 + c] = s_thr[slot][row][c];
    }
    if (lane < 40) {
      int row = lane / 5, c = lane - row * 5;
      y_out[((size_t)(r0 + row) * KSTEPS + km) * 5 + c] = s_yr[slot][row][c];
    }
  }
}

extern "C" void kernel_launch(void* const* d_in, const int* in_sizes, int n_in,
                              void* d_out, int out_size, void* d_ws, size_t ws_size,
                              hipStream_t stream) {
  const float* y0 = (const float*)d_in[0];
  const float* u_seq = (const float*)d_in[1];
  const float* dt_seq = (const float*)d_in[2];
  const float* lift_W = (const float*)d_in[3];
  const float* lift_b = (const float*)d_in[4];
  const float* W_ih = (const float*)d_in[5];
  const float* W_hh = (const float*)d_in[6];
  const float* b_ih = (const float*)d_in[7];
  const float* b_hh = (const float*)d_in[8];
  const float* head_W = (const float*)d_in[9];
  const float* head_b = (const float*)d_in[10];
  const float* jumpW = (const float*)d_in[11];

  float* y_out = (float*)d_out;                    // (4096, 512, 5)
  float* th_out = y_out + (size_t)4096 * 512 * 5;  // (4096, 512, 8)

  rnn_scan_kernel<<<dim3(512), dim3(NTH), 0, stream>>>(
      y0, u_seq, dt_seq, lift_W, lift_b, W_ih, W_hh, b_ih, b_hh, head_W,
      head_b, jumpW, y_out, th_out);
}

// Round 11
// 960.646 us; speedup vs baseline: 3.9250x; 1.8345x over previous
//
#include <hip/hip_runtime.h>

// SimpleRNN: B=4096, K=512, U=3, P=5, H=128, L=32, N_SUB=10
// FINAL (R11 = R8 restored): 256 blocks x 512 threads (8 waves), 16 batch
// rows/block, 1 block/CU. "T-scheme": all GEMMs transposed (weights = MFMA
// A-operand, activations = B-operand): D has batch-row in lane&15, out-col
// in regs+quad.
//
// R1: RK4 linear in y -> M = I5 + B*(hs*Z1)*C via T = C*B (4x4 tridiag).
// R2: double-head MFMA: every lane gets all 8 rates directly.
// R3: flux-space iteration (w~ <- G w~, G = I + hs*T*Z1); u/dt LDS ring.
// R5: v_pk_fma_f32 + op_sel broadcast for flux iter / G build / Z1 apply;
//     head as 8 independent MFMA accumulators.
// R8: bias C-folding (accumulator resets eliminated).
//
// SESSION LESSONS (measured, do not revisit):
// - Packed tree/sigm (asm VOP3P result -> v_exp_f32) FAILED on HW twice
//   (R6/R7) despite algebraic equivalence; pk<->pk couplings are safe.
// - ds_bpermute x-rebuild FAILED (pull semantics: source-side cndmask
//   cannot serve two consumers per instruction).
// - Co-residency (2 blocks/CU) is register-infeasible: total regs/wave
//   (arch+acc, unified file) ~200 > 128; VGPR cap 64 -> scratch spill
//   (R9: FETCH 4.7 GB, 4x slower). LDS weight-streaming also infeasible
//   (2 x 96 KB W_hh > 160 KB).
// - hipcc __launch_bounds__(512, k) acts as k blocks/CU: k=4 -> 64-VGPR
//   cap; k=2 -> 128 (what this body compiles to).
// - Kernel is loop-carried-latency-bound (HBM 1.8%, MFMA 12.7%, VALU 31%):
//   step = phase1 + B_h + wave-7 serial (head->theta->Z1->flux->y->x) + B_x.
//   On-chain ops cost ~3.5 cyc each; off-chain shuffling is zero-sum.

#define KSTEPS 512
#define NTH 512

typedef short s16x8 __attribute__((ext_vector_type(8)));
typedef short s16x4 __attribute__((ext_vector_type(4)));
typedef float f32x4 __attribute__((ext_vector_type(4)));
typedef float f32x2 __attribute__((ext_vector_type(2)));

__device__ __forceinline__ unsigned short f2bf(float f) {
  union { float f; unsigned u; } v; v.f = f;
  unsigned r = v.u + 0x7FFFu + ((v.u >> 16) & 1u);  // RNE
  return (unsigned short)(r >> 16);
}
__device__ __forceinline__ unsigned cvt2bf(float lo, float hi) {
  unsigned r;
  asm("v_cvt_pk_bf16_f32 %0, %1, %2" : "=v"(r) : "v"(lo), "v"(hi));
  return r;
}
__device__ __forceinline__ float ex2(float x) {
#if __has_builtin(__builtin_amdgcn_exp2f)
  return __builtin_amdgcn_exp2f(x);
#else
  return exp2f(x);
#endif
}
__device__ __forceinline__ float rcp_(float x) {
#if __has_builtin(__builtin_amdgcn_rcpf)
  return __builtin_amdgcn_rcpf(x);
#else
  return 1.0f / x;
#endif
}
__device__ __forceinline__ float sigm(float x) {
  return rcp_(1.0f + ex2(-1.44269504088896f * x));
}
__device__ __forceinline__ float tanh_(float x) {
  return fmaf(2.0f, rcp_(1.0f + ex2(-2.88539008177793f * x)), -1.0f);
}
__device__ __forceinline__ f32x4 splat4(float v) { f32x4 r = {v, v, v, v}; return r; }
__device__ __forceinline__ f32x4 MFMA(s16x8 a, s16x8 b, f32x4 c) {
  return __builtin_amdgcn_mfma_f32_16x16x32_bf16(a, b, c, 0, 0, 0);
}
__device__ __forceinline__ s16x8 bfrag_g(const float* __restrict__ src8) {
  s16x8 r;
#pragma unroll
  for (int j = 0; j < 8; ++j) r[j] = (short)f2bf(src8[j]);
  return r;
}

// ---- packed f32 math with op_sel B-broadcast ----
__device__ __forceinline__ f32x2 pkfma_blo(f32x2 a, f32x2 b, f32x2 c) {
  f32x2 d;
  asm("v_pk_fma_f32 %0, %1, %2, %3 op_sel:[0,0,0] op_sel_hi:[1,0,1]"
      : "=v"(d) : "v"(a), "v"(b), "v"(c));
  return d;
}
__device__ __forceinline__ f32x2 pkfma_bhi(f32x2 a, f32x2 b, f32x2 c) {
  f32x2 d;
  asm("v_pk_fma_f32 %0, %1, %2, %3 op_sel:[0,1,0] op_sel_hi:[1,1,1]"
      : "=v"(d) : "v"(a), "v"(b), "v"(c));
  return d;
}
__device__ __forceinline__ f32x2 pkmul_blo(f32x2 a, f32x2 b) {
  f32x2 d;
  asm("v_pk_mul_f32 %0, %1, %2 op_sel:[0,0] op_sel_hi:[1,0]"
      : "=v"(d) : "v"(a), "v"(b));
  return d;
}
__device__ __forceinline__ f32x2 pkmul_bhi(f32x2 a, f32x2 b) {
  f32x2 d;
  asm("v_pk_mul_f32 %0, %1, %2 op_sel:[0,1] op_sel_hi:[1,1]"
      : "=v"(d) : "v"(a), "v"(b));
  return d;
}
__device__ __forceinline__ f32x2 pkadd(f32x2 a, f32x2 b) {
  f32x2 d;
  asm("v_pk_add_f32 %0, %1, %2" : "=v"(d) : "v"(a), "v"(b));
  return d;
}

__global__ __launch_bounds__(NTH, 2) void rnn_scan_kernel(
    const float* __restrict__ y0, const float* __restrict__ u_seq,
    const float* __restrict__ dt_seq, const float* __restrict__ lift_W,
    const float* __restrict__ lift_b, const float* __restrict__ W_ih,
    const float* __restrict__ W_hh, const float* __restrict__ b_ih,
    const float* __restrict__ b_hh, const float* __restrict__ head_W,
    const float* __restrict__ head_b, const float* __restrict__ jumpW,
    float* __restrict__ y_out, float* __restrict__ th_out) {
  __shared__ __align__(16) unsigned short s_Ah[4096];  // h: k=128 -> 4 frags
  __shared__ __align__(16) unsigned short s_Ax[1024];  // x: k=32  -> 1 frag
  __shared__ __align__(16) float s_thr[2][16][8];      // theta ring
  __shared__ __align__(16) float s_yr[2][16][8];       // y ring
  __shared__ __align__(16) float s_ur[3][16][4];       // u/dt ring (3 slots)

  const int tid = threadIdx.x;
  const int w = tid >> 6;      // wave 0..7; wave 7 = critical wave
  const int lane = tid & 63;
  const int quad = lane >> 4;
  const int col = lane & 15;   // = batch row in the T-scheme
  const int r0 = blockIdx.x << 4;

  s16x8 zf;
#pragma unroll
  for (int j = 0; j < 8; ++j) zf[j] = 0;

  // ---- weight A-frags: A[m=out-col@lane&15][k=quad*8+j] ----
  s16x8 bih_r = bfrag_g(&W_ih[(w * 16 + col) * 32 + quad * 8]);
  s16x8 bih_z = bfrag_g(&W_ih[((8 + w) * 16 + col) * 32 + quad * 8]);
  s16x8 bih_n = bfrag_g(&W_ih[((16 + w) * 16 + col) * 32 + quad * 8]);
  s16x8 bhh_r[4], bhh_z[4], bhh_n[4], bhdF[4], bhdR[4];
#pragma unroll
  for (int s = 0; s < 4; ++s) {
    bhh_r[s] = bfrag_g(&W_hh[(w * 16 + col) * 128 + s * 32 + quad * 8]);
    bhh_z[s] = bfrag_g(&W_hh[((8 + w) * 16 + col) * 128 + s * 32 + quad * 8]);
    bhh_n[s] = bfrag_g(&W_hh[((16 + w) * 16 + col) * 128 + s * 32 + quad * 8]);
    // head rows replicated mod 4: every lane receives kf1..4 / kr1..4.
    bhdF[s] = bfrag_g(&head_W[(col & 3) * 128 + s * 32 + quad * 8]);
    bhdR[s] = bfrag_g(&head_W[(4 + (col & 3)) * 128 + s * 32 + quad * 8]);
  }
  s16x8 blft0 = (quad == 0) ? bfrag_g(&lift_W[col * 8]) : zf;
  s16x8 blft1 = (quad == 0) ? bfrag_g(&lift_W[(16 + col) * 8]) : zf;

  // ---- per-(quad,i) biases ----
  f32x4 brz_r, brz_z, bn_iv, bn_hv, lbv0, lbv1, hbF, hbR;
#pragma unroll
  for (int i = 0; i < 4; ++i) {
    int g = w * 16 + quad * 4 + i;
    brz_r[i] = b_ih[g] + b_hh[g];
    brz_z[i] = b_ih[128 + g] + b_hh[128 + g];
    bn_iv[i] = b_ih[256 + g];
    bn_hv[i] = b_hh[256 + g];
    lbv0[i] = lift_b[quad * 4 + i];
    lbv1[i] = lift_b[16 + quad * 4 + i];
    hbF[i] = head_b[i];
    hbR[i] = head_b[4 + i];
  }
  float J[15];
#pragma unroll
  for (int i = 0; i < 15; ++i) J[i] = jumpW[i];

  // producer LDS byte offsets
  const int hwoff = (((w >> 1) * 64 + ((w & 1) * 2 + (quad >> 1)) * 16 + col) << 4) +
                    ((quad & 1) << 3);
  const int xw0 = ((((quad >> 1)) * 16 + col) << 4) + ((quad & 1) << 3);
  const int xw1 = (((2 + (quad >> 1)) * 16 + col) << 4) + ((quad & 1) << 3);

  // persistent state (ar/az/angh carry bias+gh across barriers; no resets)
  f32x4 ar = brz_r, az = brz_z, angi = bn_iv, angh = bn_hv;
  f32x4 h_reg = splat4(0.0f);
  float y[5] = {0.f, 0.f, 0.f, 0.f, 0.f};

  // ---- prologue ----
  if (w == 1 && lane < 16) {
#pragma unroll
    for (int pk = 0; pk < 2; ++pk) {
      const float* up = &u_seq[((size_t)(r0 + lane) * KSTEPS + pk) * 3];
      f32x4 uv;
      uv[0] = up[0]; uv[1] = up[1]; uv[2] = up[2];
      uv[3] = dt_seq[(size_t)(r0 + lane) * KSTEPS + pk];
      *(f32x4*)&s_ur[pk][lane][0] = uv;
    }
  }
  if (w == 7) {
    float uc0 = 0.f, uc1 = 0.f, uc2 = 0.f;
    if (quad == 0) {
      const float* yp = &y0[(r0 + col) * 5];
#pragma unroll
      for (int i = 0; i < 5; ++i) y[i] = yp[i] + 0.01f;
      const float* up = &u_seq[((size_t)(r0 + col) * KSTEPS) * 3];
      uc0 = up[0]; uc1 = up[1]; uc2 = up[2];
    }
    s16x8 af = zf;
    if (quad == 0) {
      union { s16x8 v; unsigned u[4]; } afu;
      afu.u[0] = cvt2bf(uc0, uc1);
      afu.u[1] = cvt2bf(uc2, y[0]);
      afu.u[2] = cvt2bf(y[1], y[2]);
      afu.u[3] = cvt2bf(y[3], y[4]);
      af = afu.v;
    }
    f32x4 x0 = MFMA(blft0, af, lbv0);
    f32x4 x1 = MFMA(blft1, af, lbv1);
    f32x4 s0, s1;
#pragma unroll
    for (int i = 0; i < 4; ++i) {
      float v0 = x0[i]; s0[i] = v0 * sigm(v0);
      float v1 = x1[i]; s1[i] = v1 * sigm(v1);
    }
    uint2 xp0, xp1;
    xp0.x = cvt2bf(s0[0], s0[1]); xp0.y = cvt2bf(s0[2], s0[3]);
    xp1.x = cvt2bf(s1[0], s1[1]); xp1.y = cvt2bf(s1[2], s1[3]);
    *(uint2*)((char*)s_Ax + xw0) = xp0;
    *(uint2*)((char*)s_Ax + xw1) = xp1;
  }
  __syncthreads();  // B_x(0)

  int sA = 0, sB = 1, sC = 2;  // u-ring slots

#pragma unroll 1
  for (int k = 0; k < KSTEPS; ++k) {
    // ======== phase 1: gi + gates + h stage (all waves) ========
    {
      s16x8 xf = *(const s16x8*)((const char*)s_Ax + lane * 16);
      ar = MFMA(bih_r, xf, ar);        // carried C = bias + gh(k)
      az = MFMA(bih_z, xf, az);
      angi = MFMA(bih_n, xf, bn_iv);   // bias folded directly
    }
    {
      f32x4 hf;
#pragma unroll
      for (int i = 0; i < 4; ++i) {
        float r = sigm(ar[i]);
        float z = sigm(az[i]);
        float n = tanh_(fmaf(r, angh[i], angi[i]));
        float hn = fmaf(z, h_reg[i] - n, n);
        h_reg[i] = hn;
        hf[i] = hn;
      }
      uint2 hp;
      hp.x = cvt2bf(hf[0], hf[1]);
      hp.y = cvt2bf(hf[2], hf[3]);
      *(uint2*)((char*)s_Ah + hwoff) = hp;
    }
    __syncthreads();  // B_h

    // ======== phase 2 ========
    s16x8 ah[4];
#pragma unroll
    for (int s = 0; s < 4; ++s)
      ah[s] = *(const s16x8*)((const char*)s_Ah + (s * 64 + lane) * 16);

    if (w == 7) {
      __builtin_amdgcn_s_setprio(1);
      f32x4 urk = *(const f32x4*)&s_ur[sA][col][0];
      f32x4 urk1 = *(const f32x4*)&s_ur[sB][col][0];
      // head: 8 independent MFMAs
      f32x4 hdF0 = MFMA(bhdF[0], ah[0], hbF);
      f32x4 hdF1 = MFMA(bhdF[1], ah[1], splat4(0.0f));
      f32x4 hdF2 = MFMA(bhdF[2], ah[2], splat4(0.0f));
      f32x4 hdF3 = MFMA(bhdF[3], ah[3], splat4(0.0f));
      f32x4 hdR0 = MFMA(bhdR[0], ah[0], hbR);
      f32x4 hdR1 = MFMA(bhdR[1], ah[1], splat4(0.0f));
      f32x4 hdR2 = MFMA(bhdR[2], ah[2], splat4(0.0f));
      f32x4 hdR3 = MFMA(bhdR[3], ah[3], splat4(0.0f));
      // own gh(k+1) issues under head latency, biases C-folded
      ar = MFMA(bhh_r[0], ah[0], brz_r);
      az = MFMA(bhh_z[0], ah[0], brz_z);
      angh = MFMA(bhh_n[0], ah[0], bn_hv);
#pragma unroll
      for (int s = 1; s < 4; ++s) {
        ar = MFMA(bhh_r[s], ah[s], ar);
        az = MFMA(bhh_z[s], ah[s], az);
        angh = MFMA(bhh_n[s], ah[s], angh);
      }
      f32x4 hdF = (hdF0 + hdF1) + (hdF2 + hdF3);
      f32x4 hdR = (hdR0 + hdR1) + (hdR2 + hdR3);
      f32x4 tvF, tvR;
#pragma unroll
      for (int i = 0; i < 4; ++i) {
        tvF[i] = fmaf(2.99f, sigm(hdF[i]), 0.01f);
        tvR[i] = fmaf(2.99f, sigm(hdR[i]), 0.01f);
      }
      const int slot = k & 1;
      if (quad == 0) {
        *(f32x4*)&s_thr[slot][col][0] = tvF;
        *(f32x4*)&s_thr[slot][col][4] = tvR;
      }
      const float F0 = tvF[0], F1 = tvF[1], F2 = tvF[2], F3 = tvF[3];
      const float R0 = tvR[0], R1 = tvR[1], R2 = tvR[2], R3 = tvR[3];
      // jump
#pragma unroll
      for (int i = 0; i < 5; ++i)
        y[i] += urk[0] * J[i] + urk[1] * J[5 + i] + urk[2] * J[10 + i];
      const float hs = urk[3] * 0.1f;

      // ---- Z1 = I + c2 T(I + c3 T(I + c4 T)) (scalar; band-sparse) ----
      const float TD0 = -(F0 + R0), TD1 = -(F1 + R1), TD2 = -(F2 + R2), TD3 = -(F3 + R3);
      const float c4 = 0.25f * hs, c3 = hs * (1.0f / 3.0f), c2 = 0.5f * hs;
      const float d30 = fmaf(c4, TD0, 1.f), d31 = fmaf(c4, TD1, 1.f);
      const float d32 = fmaf(c4, TD2, 1.f), d33 = fmaf(c4, TD3, 1.f);
      const float l31 = c4 * F1, l32 = c4 * F2, l33 = c4 * F3;
      const float u30 = c4 * R0, u31 = c4 * R1, u32 = c4 * R2;
      const float w300 = fmaf(TD0, d30, R0 * l31);
      const float w301 = fmaf(TD0, u30, R0 * d31);
      const float w302 = R0 * u31;
      const float w310 = fmaf(F1, d30, TD1 * l31);
      const float w311 = fmaf(F1, u30, fmaf(TD1, d31, R1 * l32));
      const float w312 = fmaf(TD1, u31, R1 * d32);
      const float w313 = R1 * u32;
      const float w320 = F2 * l31;
      const float w321 = fmaf(F2, d31, TD2 * l32);
      const float w322 = fmaf(F2, u31, fmaf(TD2, d32, R2 * l33));
      const float w323 = fmaf(TD2, u32, R2 * d33);
      const float w331 = F3 * l32;
      const float w332 = fmaf(F3, d32, TD3 * l33);
      const float w333 = fmaf(F3, u32, TD3 * d33);
      const float e20 = fmaf(c3, w300, 1.f), e21 = fmaf(c3, w311, 1.f);
      const float e22 = fmaf(c3, w322, 1.f), e23 = fmaf(c3, w333, 1.f);
      const float a201 = c3 * w301, a202 = c3 * w302;
      const float a210 = c3 * w310, a212 = c3 * w312, a213 = c3 * w313;
      const float a220 = c3 * w320, a221 = c3 * w321, a223 = c3 * w323;
      const float a231 = c3 * w331, a232 = c3 * w332;
      const float w200 = fmaf(TD0, e20, R0 * a210);
      const float w201 = fmaf(TD0, a201, R0 * e21);
      const float w202 = fmaf(TD0, a202, R0 * a212);
      const float w203 = R0 * a213;
      const float w210 = fmaf(F1, e20, fmaf(TD1, a210, R1 * a220));
      const float w211 = fmaf(F1, a201, fmaf(TD1, e21, R1 * a221));
      const float w212 = fmaf(F1, a202, fmaf(TD1, a212, R1 * e22));
      const float w213 = fmaf(TD1, a213, R1 * a223);
      const float w220 = fmaf(F2, a210, TD2 * a220);
      const float w221 = fmaf(F2, e21, fmaf(TD2, a221, R2 * a231));
      const float w222 = fmaf(F2, a212, fmaf(TD2, e22, R2 * a232));
      const float w223 = fmaf(F2, a213, fmaf(TD2, a223, R2 * e23));
      const float w230 = F3 * a220;
      const float w231 = fmaf(F3, a221, TD3 * a231);
      const float w232 = fmaf(F3, e22, TD3 * a232);
      const float w233 = fmaf(F3, a223, TD3 * e23);
      const float z100 = fmaf(c2, w200, 1.f), z101 = c2 * w201, z102 = c2 * w202, z103 = c2 * w203;
      const float z110 = c2 * w210, z111 = fmaf(c2, w211, 1.f), z112 = c2 * w212, z113 = c2 * w213;
      const float z120 = c2 * w220, z121 = c2 * w221, z122 = fmaf(c2, w222, 1.f), z123 = c2 * w223;
      const float z130 = c2 * w230, z131 = c2 * w231, z132 = c2 * w232, z133 = fmaf(c2, w233, 1.f);

      // ---- packed Z1 columns ----
      f32x2 cZa0 = {z100, z110}, cZb0 = {z120, z130};
      f32x2 cZa1 = {z101, z111}, cZb1 = {z121, z131};
      f32x2 cZa2 = {z102, z112}, cZb2 = {z122, z132};
      f32x2 cZa3 = {z103, z113}, cZb3 = {z123, z133};

      const float FH0 = hs * F0, FH1 = hs * F1, FH2 = hs * F2, FH3 = hs * F3;
      const float RH0 = hs * R0, RH1 = hs * R1, RH2 = hs * R2, RH3 = hs * R3;
      const float TDH0 = -(FH0 + RH0), TDH1 = -(FH1 + RH1);
      const float TDH2 = -(FH2 + RH2), TDH3 = -(FH3 + RH3);
      f32x2 pA01 = {TDH0, FH1}, pB01 = {RH0, TDH1}, pC01 = {0.f, RH1};
      f32x2 pA23 = {FH2, 0.f}, pB23 = {TDH2, FH3}, pC23 = {RH2, TDH3};
      f32x2 cG0a = pkfma_blo(pC01, cZb0, pkfma_bhi(pB01, cZa0, pkmul_blo(pA01, cZa0)));
      f32x2 cG1a = pkfma_blo(pC01, cZb1, pkfma_bhi(pB01, cZa1, pkmul_blo(pA01, cZa1)));
      f32x2 cG2a = pkfma_blo(pC01, cZb2, pkfma_bhi(pB01, cZa2, pkmul_blo(pA01, cZa2)));
      f32x2 cG3a = pkfma_blo(pC01, cZb3, pkfma_bhi(pB01, cZa3, pkmul_blo(pA01, cZa3)));
      f32x2 cG0b = pkfma_bhi(pC23, cZb0, pkfma_blo(pB23, cZb0, pkmul_bhi(pA23, cZa0)));
      f32x2 cG1b = pkfma_bhi(pC23, cZb1, pkfma_blo(pB23, cZb1, pkmul_bhi(pA23, cZa1)));
      f32x2 cG2b = pkfma_bhi(pC23, cZb2, pkfma_blo(pB23, cZb2, pkmul_bhi(pA23, cZa2)));
      f32x2 cG3b = pkfma_bhi(pC23, cZb3, pkfma_blo(pB23, cZb3, pkmul_bhi(pA23, cZa3)));
      cG0a[0] += 1.0f;
      cG1a[1] += 1.0f;
      cG2b[0] += 1.0f;
      cG3b[1] += 1.0f;

      // w~0 = hs*C*y (clamp is a no-op: M>=0 entrywise, y>=0)
      const float w0v = fmaf(FH0, y[0], -(RH0 * y[1]));
      const float w1v = fmaf(FH1, y[1], -(RH1 * y[2]));
      const float w2v = fmaf(FH2, y[2], -(RH2 * y[3]));
      const float w3v = fmaf(FH3, y[3], -(RH3 * y[4]));
      f32x2 W01 = {w0v, w1v}, W23 = {w2v, w3v};
      f32x2 A01 = W01, A23 = W23;
#pragma unroll
      for (int ss = 0; ss < 9; ++ss) {
        f32x2 m01 = pkfma_blo(cG0a, W01,
                    pkfma_bhi(cG1a, W01,
                    pkfma_blo(cG2a, W23, pkmul_bhi(cG3a, W23))));
        f32x2 m23 = pkfma_blo(cG0b, W01,
                    pkfma_bhi(cG1b, W01,
                    pkfma_blo(cG2b, W23, pkmul_bhi(cG3b, W23))));
        W01 = m01; W23 = m23;
        A01 = pkadd(A01, m01); A23 = pkadd(A23, m23);
      }
      f32x2 s01 = pkfma_blo(cZa0, A01,
                  pkfma_bhi(cZa1, A01,
                  pkfma_blo(cZa2, A23, pkmul_bhi(cZa3, A23))));
      f32x2 s23 = pkfma_blo(cZb0, A01,
                  pkfma_bhi(cZb1, A01,
                  pkfma_blo(cZb2, A23, pkmul_bhi(cZb3, A23))));
      const float s0f = s01[0], s1f = s01[1], s2f = s23[0], s3f = s23[1];
      y[0] -= s0f;
      y[1] += s0f - s1f;
      y[2] += s1f - s2f;
      y[3] += s2f - s3f;
      y[4] += s3f;
      if (quad == 0) {
        *(f32x4*)&s_yr[slot][col][0] = *(const f32x4*)&y[0];
        s_yr[slot][col][4] = y[4];
      }
      // feat(k+1) -> liftT -> silu -> x stage
      if (k + 1 < KSTEPS) {
        s16x8 af = zf;
        if (quad == 0) {
          union { s16x8 v; unsigned u[4]; } afu;
          afu.u[0] = cvt2bf(urk1[0], urk1[1]);
          afu.u[1] = cvt2bf(urk1[2], y[0]);
          afu.u[2] = cvt2bf(y[1], y[2]);
          afu.u[3] = cvt2bf(y[3], y[4]);
          af = afu.v;
        }
        f32x4 x0 = MFMA(blft0, af, lbv0);
        f32x4 x1 = MFMA(blft1, af, lbv1);
        f32x4 s0, s1;
#pragma unroll
        for (int i = 0; i < 4; ++i) {
          float v0 = x0[i]; s0[i] = v0 * sigm(v0);
          float v1 = x1[i]; s1[i] = v1 * sigm(v1);
        }
        uint2 xp0, xp1;
        xp0.x = cvt2bf(s0[0], s0[1]); xp0.y = cvt2bf(s0[2], s0[3]);
        xp1.x = cvt2bf(s1[0], s1[1]); xp1.y = cvt2bf(s1[2], s1[3]);
        *(uint2*)((char*)s_Ax + xw0) = xp0;
        *(uint2*)((char*)s_Ax + xw1) = xp1;
      }
      __builtin_amdgcn_s_setprio(0);
    } else {
      // gh(k+1) for this wave's tile, biases C-folded
      ar = MFMA(bhh_r[0], ah[0], brz_r);
      az = MFMA(bhh_z[0], ah[0], brz_z);
      angh = MFMA(bhh_n[0], ah[0], bn_hv);
#pragma unroll
      for (int s = 1; s < 4; ++s) {
        ar = MFMA(bhh_r[s], ah[s], ar);
        az = MFMA(bhh_z[s], ah[s], az);
        angh = MFMA(bhh_n[s], ah[s], angh);
      }
      if (w == 1 && lane < 16) {  // stage u/dt for step k+2
        int kn2 = (k + 2 < KSTEPS) ? k + 2 : KSTEPS - 1;
        const float* up = &u_seq[((size_t)(r0 + lane) * KSTEPS + kn2) * 3];
        f32x4 uv;
        uv[0] = up[0]; uv[1] = up[1]; uv[2] = up[2];
        uv[3] = dt_seq[(size_t)(r0 + lane) * KSTEPS + kn2];
        *(f32x4*)&s_ur[sC][lane][0] = uv;
      }
      if (w == 0 && k > 0) {  // store step k-1 outputs from the ring
        const int km = k - 1, slot = km & 1;
#pragma unroll
        for (int rep = 0; rep < 2; ++rep) {
          int idx = lane + rep * 64;
          int row = idx >> 3, c = idx & 7;
          th_out[((size_t)(r0 + row) * KSTEPS + km) * 8 + c] = s_thr[slot][row][c];
        }
        {
          int idx = lane;
          int row = idx / 5, c = idx - row * 5;
          y_out[((size_t)(r0 + row) * KSTEPS + km) * 5 + c] = s_yr[slot][row][c];
        }
        if (lane < 16) {
          int idx = 64 + lane;
          int row = idx / 5, c = idx - row * 5;
          y_out[((size_t)(r0 + row) * KSTEPS + km) * 5 + c] = s_yr[slot][row][c];
        }
      }
    }
    __syncthreads();  // B_x: x(k+1) staged, s_Ah + s_ur[sC] reusable
    int st = sA; sA = sB; sB = sC; sC = st;
  }

  // flush step-511 outputs
  if (w == 0) {
    const int km = KSTEPS - 1, slot = km & 1;
#pragma unroll
    for (int rep = 0; rep < 2; ++rep) {
      int idx = lane + rep * 64;
      int row = idx >> 3, c = idx & 7;
      th_out[((size_t)(r0 + row) * KSTEPS + km) * 8 + c] = s_thr[slot][row][c];
    }
    {
      int idx = lane;
      int row = idx / 5, c = idx - row * 5;
      y_out[((size_t)(r0 + row) * KSTEPS + km) * 5 + c] = s_yr[slot][row][c];
    }
    if (lane < 16) {
      int idx = 64 + lane;
      int row = idx / 5, c = idx - row * 5;
      y_out[((size_t)(r0 + row) * KSTEPS + km) * 5 + c] = s_yr[slot][row][c];
    }
  }
}

extern "C" void kernel_launch(void* const* d_in, const int* in_sizes, int n_in,
                              void* d_out, int out_size, void* d_ws, size_t ws_size,
                              hipStream_t stream) {
  const float* y0 = (const float*)d_in[0];
  const float* u_seq = (const float*)d_in[1];
  const float* dt_seq = (const float*)d_in[2];
  const float* lift_W = (const float*)d_in[3];
  const float* lift_b = (const float*)d_in[4];
  const float* W_ih = (const float*)d_in[5];
  const float* W_hh = (const float*)d_in[6];
  const float* b_ih = (const float*)d_in[7];
  const float* b_hh = (const float*)d_in[8];
  const float* head_W = (const float*)d_in[9];
  const float* head_b = (const float*)d_in[10];
  const float* jumpW = (const float*)d_in[11];

  float* y_out = (float*)d_out;                    // (4096, 512, 5)
  float* th_out = y_out + (size_t)4096 * 512 * 5;  // (4096, 512, 8)

  rnn_scan_kernel<<<dim3(256), dim3(NTH), 0, stream>>>(
      y0, u_seq, dt_seq, lift_W, lift_b, W_ih, W_hh, b_ih, b_hh, head_W,
      head_b, jumpW, y_out, th_out);
}